// Round 7
// baseline (471.178 us; speedup 1.0000x reference)
//
#include <hip/hip_runtime.h>
#include <hip/hip_cooperative_groups.h>
#include <math.h>

namespace cg = cooperative_groups;

#define NPTS   100000
#define NRAYS  4096
#define KTOP   10
#define KMER   12
#define CAP    128
#define LCAP   12

#define GB     512                // persistent grid: 2 blocks/CU guaranteed resident

// scan: 16 pts/lane, unit = 4096 pts x 64 rays, 25*64 = 1600 units
#define PSC    16
#define SBLK   25
#define RCS    64
#define RPBS   (NRAYS / RCS)      // 64
#define USCAN  (SBLK * RCS)

// theta sample: 8 pts/lane, unit = 2048 pts x 64 rays, 16*64 = 1024 units
#define PTH    8
#define TBLK   16
#define NPART  (TBLK * 4)         // 64 parts of 512
#define RCT    64
#define RPBT   (NRAYS / RCT)      // 64
#define UTH    (TBLK * RCT)

static_assert(SBLK * 4096 >= NPTS, "scan covers all points");
static_assert(TBLK * 2048 <= NPTS, "theta sample within real points");

__device__ __forceinline__ float4 make_center(const float* __restrict__ ro,
                                              const float* __restrict__ rd,
                                              int ray, float w) {
    float ox = ro[3 * ray + 0], oy = ro[3 * ray + 1], oz = ro[3 * ray + 2];
    float dx = rd[3 * ray + 0], dy = rd[3 * ray + 1], dz = rd[3 * ray + 2];
    float cx, cy, cz;
    {
#pragma clang fp contract(off)
        cx = ox + dx * 3.0f;
        cy = oy + dy * 3.0f;
        cz = oz + dz * 3.0f;
    }
    return make_float4(cx, cy, cz, w);
}

__device__ __forceinline__ float sigm(float x) { return 1.0f / (1.0f + expf(-x)); }

__device__ __forceinline__ unsigned long long mkkey(float sc, int id, bool v) {
    unsigned u = __float_as_uint(sc);
    u = (u & 0x80000000u) ? ~u : (u | 0x80000000u);    // order-preserving f32->u32
    unsigned long long k = ((unsigned long long)u << 32) | (unsigned)(~id);
    return v ? k : 0ull;                               // smaller id -> larger key
}

// ---------------------------------------------------------------------------
// One persistent cooperative kernel; phases separated by grid.sync().
//   A: theta part maxima over 32768-pt sample  -> pm[64][NRAYS]
//   B: theta[ray] = 10th-largest of 64 part maxima; cnt = 0
//   C: scan all points, emit score>=theta to per-ray LDS, bulk flush -> cand
//   D: wave-per-ray merge: top-12 f32 -> exact f64 re-rank -> top-10 -> rgb
// ---------------------------------------------------------------------------
__global__ __launch_bounds__(256, 2)
void fused_kernel(const float* __restrict__ ro, const float* __restrict__ rd,
                  const float* __restrict__ xyz, const float* __restrict__ fdc,
                  const float* __restrict__ opac, float* __restrict__ pm,
                  float* __restrict__ theta, int* __restrict__ cnt,
                  float2* __restrict__ cand, float* __restrict__ out) {
    __shared__ float4 rsh[RPBS];
    __shared__ int    lcnt[RPBS];
    __shared__ float2 lbuf[RPBS][LCAP];

    const int tid = threadIdx.x, wave = tid >> 6, lane = tid & 63;
    cg::grid_group grid = cg::this_grid();

    // ---- Phase A: theta part maxima --------------------------------------
    for (int u = blockIdx.x; u < UTH; u += GB) {
        const int pblk = u & (TBLK - 1), rchunk = u >> 4;
        const int rbase = rchunk * RPBT;
        __syncthreads();
        if (tid < RPBT) rsh[tid] = make_center(ro, rd, rbase + tid, 0.0f);

        const int id0 = pblk * 2048 + wave * 512 + lane;     // < 32768, all real
        float px[PTH], py[PTH], pz[PTH], pw[PTH];
#pragma unroll
        for (int v = 0; v < PTH; ++v) {
            int id = id0 + v * 64;
            float x = xyz[3 * id + 0], y = xyz[3 * id + 1], z = xyz[3 * id + 2];
            px[v] = x; py[v] = y; pz[v] = z;
            pw[v] = -0.5f * fmaf(x, x, fmaf(y, y, z * z));
        }
        __syncthreads();

        const int part = pblk * 4 + wave;
        for (int r = 0; r < RPBT; r += 4) {
            float4 r0 = rsh[r], r1 = rsh[r + 1], r2 = rsh[r + 2], r3 = rsh[r + 3];
            float m0 = -INFINITY, m1 = -INFINITY, m2 = -INFINITY, m3 = -INFINITY;
#pragma unroll
            for (int v = 0; v < PTH; ++v) {
                float t0 = fmaf(pz[v], r0.z, pw[v]); t0 = fmaf(py[v], r0.y, t0); t0 = fmaf(px[v], r0.x, t0);
                m0 = fmaxf(m0, t0);
                float t1 = fmaf(pz[v], r1.z, pw[v]); t1 = fmaf(py[v], r1.y, t1); t1 = fmaf(px[v], r1.x, t1);
                m1 = fmaxf(m1, t1);
                float t2 = fmaf(pz[v], r2.z, pw[v]); t2 = fmaf(py[v], r2.y, t2); t2 = fmaf(px[v], r2.x, t2);
                m2 = fmaxf(m2, t2);
                float t3 = fmaf(pz[v], r3.z, pw[v]); t3 = fmaf(py[v], r3.y, t3); t3 = fmaf(px[v], r3.x, t3);
                m3 = fmaxf(m3, t3);
            }
#pragma unroll
            for (int off = 1; off < 64; off <<= 1) {
                m0 = fmaxf(m0, __shfl_xor(m0, off));
                m1 = fmaxf(m1, __shfl_xor(m1, off));
                m2 = fmaxf(m2, __shfl_xor(m2, off));
                m3 = fmaxf(m3, __shfl_xor(m3, off));
            }
            if (lane == 0)
                *(float4*)&pm[part * NRAYS + rbase + r] = make_float4(m0, m1, m2, m3);
        }
    }

    __threadfence();
    grid.sync();

    // ---- Phase B: theta reduce (blocks 0..15) ----------------------------
    for (int u = blockIdx.x; u < NRAYS / 256; u += GB) {
        const int ray = u * 256 + tid;
        float vs[KTOP];
#pragma unroll
        for (int j = 0; j < KTOP; ++j) vs[j] = -INFINITY;
#pragma unroll 1
        for (int g = 0; g < NPART / 8; ++g) {
            float m[8];
#pragma unroll
            for (int j = 0; j < 8; ++j) m[j] = pm[(g * 8 + j) * NRAYS + ray];
#pragma unroll
            for (int j = 0; j < 8; ++j) {
                float v = m[j];
                if (v > vs[KTOP - 1]) {
#pragma unroll
                    for (int s = KTOP - 1; s >= 1; --s) {
                        bool up = v > vs[s - 1], here = v > vs[s];
                        vs[s] = up ? vs[s - 1] : (here ? v : vs[s]);
                    }
                    if (v > vs[0]) vs[0] = v;
                }
            }
        }
        theta[ray] = vs[KTOP - 1];
        cnt[ray] = 0;
    }

    __threadfence();
    grid.sync();

    // ---- Phase C: guarded scan -------------------------------------------
    for (int u = blockIdx.x; u < USCAN; u += GB) {
        const int pblk = u % SBLK, rchunk = u / SBLK;
        const int rbase = rchunk * RPBS;
        __syncthreads();
        if (tid < RPBS) {
            rsh[tid] = make_center(ro, rd, rbase + tid, theta[rbase + tid]);
            lcnt[tid] = 0;
        }

        const int id0 = pblk * 4096 + wave * 1024 + lane;
        float px[PSC], py[PSC], pz[PSC], pw[PSC];
#pragma unroll
        for (int v = 0; v < PSC; ++v) {
            int id = id0 + v * 64;
            bool valid = (id < NPTS);
            int idc = valid ? id : 0;
            float x = xyz[3 * idc + 0], y = xyz[3 * idc + 1], z = xyz[3 * idc + 2];
            px[v] = x; py[v] = y; pz[v] = z;
            pw[v] = valid ? -0.5f * fmaf(x, x, fmaf(y, y, z * z)) : -INFINITY;
        }
        __syncthreads();

        float4 rp = rsh[0], rp1 = rsh[1];
        for (int r = 0; r < RPBS; ++r) {
            float4 rp2 = rsh[(r + 2) & (RPBS - 1)];    // 2-ahead prefetch
            float s[PSC];
#pragma unroll
            for (int v = 0; v < PSC; ++v) {
                float t = fmaf(pz[v], rp.z, pw[v]);
                t = fmaf(py[v], rp.y, t);
                t = fmaf(px[v], rp.x, t);
                s[v] = t;
            }
            float a0 = fmaxf(fmaxf(s[0], s[1]), s[2]);
            float a1 = fmaxf(fmaxf(s[3], s[4]), s[5]);
            float a2 = fmaxf(fmaxf(s[6], s[7]), s[8]);
            float a3 = fmaxf(fmaxf(s[9], s[10]), s[11]);
            float a4 = fmaxf(fmaxf(s[12], s[13]), s[14]);
            float b0 = fmaxf(fmaxf(a0, a1), a2);
            float b1 = fmaxf(fmaxf(a3, a4), s[15]);
            float hm = fmaxf(b0, b1);

            if (__ballot(hm >= rp.w)) {
#pragma unroll
                for (int v = 0; v < PSC; ++v) {
                    if (s[v] >= rp.w) {
                        int slot = atomicAdd(&lcnt[r], 1);        // LDS atomic
                        float2 e = make_float2(s[v], __int_as_float(id0 + v * 64));
                        if (slot < LCAP) {
                            lbuf[r][slot] = e;
                        } else {                                  // ~never
                            int gs = atomicAdd(&cnt[rbase + r], 1);
                            if (gs < CAP) cand[((rbase + r) << 7) + gs] = e;
                        }
                    }
                }
            }
            rp = rp1; rp1 = rp2;
        }

        __syncthreads();
        if (tid < RPBS) {                              // bulk flush: 1 atomic/ray
            int n = lcnt[tid];
            n = n < LCAP ? n : LCAP;
            if (n > 0) {
                const int rayid = rbase + tid;
                int base = atomicAdd(&cnt[rayid], n);
                for (int j = 0; j < n; ++j) {
                    int slot = base + j;
                    if (slot < CAP) cand[(rayid << 7) + slot] = lbuf[tid][j];
                }
            }
        }
    }

    __threadfence();
    grid.sync();

    // ---- Phase D: wave-per-ray merge -------------------------------------
    for (int ray = blockIdx.x * 4 + wave; ray < NRAYS; ray += GB * 4) {
        int n = cnt[ray];
        n = n < CAP ? n : CAP;

        const float2* cl = cand + (ray << 7);
        float2 e0 = cl[lane];                          // coalesced 512B wave-load
        float2 e1 = cl[64 + lane];
        int id0 = __float_as_int(e0.y), id1 = __float_as_int(e1.y);

        unsigned long long k0 = mkkey(e0.x, id0, lane < n);
        unsigned long long k1 = mkkey(e1.x, id1, lane + 64 < n);

        int sel = -1;                                  // lane j holds j-th best id
        unsigned long long kl = k0 > k1 ? k0 : k1;
#pragma unroll
        for (int j = 0; j < KMER; ++j) {
            unsigned long long m = kl;
#pragma unroll
            for (int off = 1; off < 64; off <<= 1) {
                unsigned long long o = __shfl_xor(m, off);
                m = m > o ? m : o;
            }
            bool win = (kl == m) && (m != 0ull);
            int wid = (k0 >= k1) ? id0 : id1;
            unsigned long long wmask = __ballot(win);
            int wl = __ffsll(wmask) - 1;               // unique winner (keys unique)
            int bid = __shfl(wid, wl & 63);
            if (m == 0ull) bid = -1;
            if (lane == j) sel = bid;
            if (win) {
                if (k0 >= k1) k0 = 0ull; else k1 = 0ull;
                kl = k0 > k1 ? k0 : k1;
            }
        }

        float ox = ro[3 * ray + 0], oy = ro[3 * ray + 1], oz = ro[3 * ray + 2];
        float dx = rd[3 * ray + 0], dy = rd[3 * ray + 1], dz = rd[3 * ray + 2];
        float cxf, cyf, czf;
        {
#pragma clang fp contract(off)
            cxf = ox + dx * 3.0f;
            cyf = oy + dy * 3.0f;
            czf = oz + dz * 3.0f;
        }
        double Cx = (double)cxf, Cy = (double)cyf, Cz = (double)czf;
        double cn = Cx * Cx + Cy * Cy + Cz * Cz;

        bool valid = (lane < KMER) && (sel >= 0);
        int pid = valid ? sel : 0;
        double X = (double)xyz[3 * pid + 0];
        double Y = (double)xyz[3 * pid + 1];
        double Z = (double)xyz[3 * pid + 2];
        double sq = valid ? (cn + (X * X + Y * Y + Z * Z) - 2.0 * (Cx * X + Cy * Y + Cz * Z))
                          : (double)INFINITY;
        int cid = valid ? sel : 0x7fffffff;

        int rank = 0;
#pragma unroll
        for (int k = 0; k < KMER; ++k) {               // rank among the 12
            double sk = __shfl(sq, k);
            int    ik = __shfl(cid, k);
            if ((sk < sq) || (sk == sq && ik < cid)) ++rank;
        }

        bool take = valid && (rank < KTOP);
        float w = 0.0f, rr = 0.0f, gg = 0.0f, bb = 0.0f;
        if (take) {                                    // parallel gathers, 10 lanes
            float dd = sqrtf(fmaxf((float)sq, 0.0f));
            w  = expf(-0.1f * dd) * sigm(opac[pid]);
            rr = w * sigm(fdc[3 * pid + 0]);
            gg = w * sigm(fdc[3 * pid + 1]);
            bb = w * sigm(fdc[3 * pid + 2]);
        }
#pragma unroll
        for (int off = 1; off < 64; off <<= 1) {
            w  += __shfl_xor(w,  off);
            rr += __shfl_xor(rr, off);
            gg += __shfl_xor(gg, off);
            bb += __shfl_xor(bb, off);
        }
        if (lane == 0) {
            float inv = 1.0f / (w + 1e-8f);
            out[3 * ray + 0] = rr * inv;
            out[3 * ray + 1] = gg * inv;
            out[3 * ray + 2] = bb * inv;
        }
    }
}

// ---------------------------------------------------------------------------
extern "C" void kernel_launch(void* const* d_in, const int* in_sizes, int n_in,
                              void* d_out, int out_size, void* d_ws, size_t ws_size,
                              hipStream_t stream) {
    const float* rays_o = (const float*)d_in[0];
    const float* rays_d = (const float*)d_in[1];
    const float* xyz    = (const float*)d_in[2];
    const float* fdc    = (const float*)d_in[3];
    const float* opac   = (const float*)d_in[4];
    float* out = (float*)d_out;

    // ws: pm 1.0MB | theta 16KB | cnt 16KB | cand 4.0MB  (~5.1MB total)
    char* w = (char*)d_ws;
    float*  pm    = (float*)w;   w += (size_t)NPART * NRAYS * 4;
    float*  theta = (float*)w;   w += (size_t)NRAYS * 4;
    int*    cnt   = (int*)w;     w += (size_t)NRAYS * 4;
    float2* cand  = (float2*)w;

    void* args[] = {(void*)&rays_o, (void*)&rays_d, (void*)&xyz, (void*)&fdc,
                    (void*)&opac, (void*)&pm, (void*)&theta, (void*)&cnt,
                    (void*)&cand, (void*)&out};
    hipLaunchCooperativeKernel((const void*)fused_kernel, dim3(GB), dim3(256),
                               args, 0, stream);
}

// Round 8
// 179.495 us; speedup vs baseline: 2.6250x; 2.6250x over previous
//
#include <hip/hip_runtime.h>
#include <math.h>

#define NPTS   100000
#define NRAYS  4096
#define KTOP   10
#define KMER   12
#define CAP    128
#define LCAP   12

// scan: 16 pts/lane (8 packed pairs), blocks of 256 = 4096 pts, 25 blocks
#define PPAIR  8
#define SBLK   25
#define RCS    64                 // ray chunks for scan
#define RPBS   (NRAYS / RCS)      // 64 rays per scan block

// theta sample: 8 pts/lane (4 pairs), 16 blocks of 2048 = 32768 pts, 64 parts
#define TPAIR  4
#define TBLK   16
#define NPART  (TBLK * 4)         // 64 parts of 512
#define RCT    64
#define RPBT   (NRAYS / RCT)      // 64 rays per theta block

typedef float v2f __attribute__((ext_vector_type(2)));

static_assert(SBLK * 4096 >= NPTS, "scan covers all points");
static_assert(TBLK * 2048 <= NPTS, "theta sample within real points");

__device__ __forceinline__ float4 make_center(const float* __restrict__ ro,
                                              const float* __restrict__ rd,
                                              int ray, float w) {
    float ox = ro[3 * ray + 0], oy = ro[3 * ray + 1], oz = ro[3 * ray + 2];
    float dx = rd[3 * ray + 0], dy = rd[3 * ray + 1], dz = rd[3 * ray + 2];
    float cx, cy, cz;
    {
#pragma clang fp contract(off)
        cx = ox + dx * 3.0f;
        cy = oy + dy * 3.0f;
        cz = oz + dz * 3.0f;
    }
    return make_float4(cx, cy, cz, w);
}

__device__ __forceinline__ float sigm(float x) { return 1.0f / (1.0f + expf(-x)); }

__device__ __forceinline__ unsigned long long mkkey(float sc, int id, bool v) {
    unsigned u = __float_as_uint(sc);
    u = (u & 0x80000000u) ? ~u : (u | 0x80000000u);    // order-preserving f32->u32
    unsigned long long k = ((unsigned long long)u << 32) | (unsigned)(~id);
    return v ? k : 0ull;                               // smaller id -> larger key
}

// ---------------------------------------------------------------------------
// theta_part: 8 pts/lane as 4 packed pairs (v_pk_fma_f32), part = wave's 512
// pts, ray centers in LDS, 4-ray-interleaved butterfly max -> pm[part][ray].
// pblk==0 blocks also zero cnt for their ray chunk.
// ---------------------------------------------------------------------------
__global__ __launch_bounds__(256) void theta_part_kernel(const float* __restrict__ xyz,
                                                         const float* __restrict__ ro,
                                                         const float* __restrict__ rd,
                                                         float* __restrict__ pm,
                                                         int* __restrict__ cnt) {
    __shared__ float4 rsh[RPBT];
    const int pblk = blockIdx.x, rchunk = blockIdx.y;
    const int tid = threadIdx.x, wave = tid >> 6, lane = tid & 63;
    const int rbase = rchunk * RPBT;

    if (tid < RPBT) rsh[tid] = make_center(ro, rd, rbase + tid, 0.0f);
    if (pblk == 0 && tid < RPBT) cnt[rbase + tid] = 0;

    const int id0 = pblk * 2048 + wave * 512 + lane;   // < 32768, all real
    v2f px[TPAIR], py[TPAIR], pz[TPAIR], pw[TPAIR];
#pragma unroll
    for (int u = 0; u < TPAIR; ++u) {
        int ia = id0 + (2 * u) * 64, ib = id0 + (2 * u + 1) * 64;
        float xa = xyz[3 * ia + 0], ya = xyz[3 * ia + 1], za = xyz[3 * ia + 2];
        float xb = xyz[3 * ib + 0], yb = xyz[3 * ib + 1], zb = xyz[3 * ib + 2];
        px[u] = (v2f){xa, xb}; py[u] = (v2f){ya, yb}; pz[u] = (v2f){za, zb};
        pw[u] = (v2f){-0.5f * fmaf(xa, xa, fmaf(ya, ya, za * za)),
                      -0.5f * fmaf(xb, xb, fmaf(yb, yb, zb * zb))};
    }
    __syncthreads();

    const int part = pblk * 4 + wave;
    for (int r = 0; r < RPBT; r += 4) {
        float4 r0 = rsh[r], r1 = rsh[r + 1], r2 = rsh[r + 2], r3 = rsh[r + 3];
        v2f a0 = (v2f){-INFINITY, -INFINITY}, a1 = a0, a2 = a0, a3 = a0;
#pragma unroll
        for (int u = 0; u < TPAIR; ++u) {
            v2f t0 = __builtin_elementwise_fma(pz[u], (v2f){r0.z, r0.z}, pw[u]);
            t0 = __builtin_elementwise_fma(py[u], (v2f){r0.y, r0.y}, t0);
            t0 = __builtin_elementwise_fma(px[u], (v2f){r0.x, r0.x}, t0);
            a0 = __builtin_elementwise_max(a0, t0);
            v2f t1 = __builtin_elementwise_fma(pz[u], (v2f){r1.z, r1.z}, pw[u]);
            t1 = __builtin_elementwise_fma(py[u], (v2f){r1.y, r1.y}, t1);
            t1 = __builtin_elementwise_fma(px[u], (v2f){r1.x, r1.x}, t1);
            a1 = __builtin_elementwise_max(a1, t1);
            v2f t2 = __builtin_elementwise_fma(pz[u], (v2f){r2.z, r2.z}, pw[u]);
            t2 = __builtin_elementwise_fma(py[u], (v2f){r2.y, r2.y}, t2);
            t2 = __builtin_elementwise_fma(px[u], (v2f){r2.x, r2.x}, t2);
            a2 = __builtin_elementwise_max(a2, t2);
            v2f t3 = __builtin_elementwise_fma(pz[u], (v2f){r3.z, r3.z}, pw[u]);
            t3 = __builtin_elementwise_fma(py[u], (v2f){r3.y, r3.y}, t3);
            t3 = __builtin_elementwise_fma(px[u], (v2f){r3.x, r3.x}, t3);
            a3 = __builtin_elementwise_max(a3, t3);
        }
        float m0 = fmaxf(a0.x, a0.y), m1 = fmaxf(a1.x, a1.y);
        float m2 = fmaxf(a2.x, a2.y), m3 = fmaxf(a3.x, a3.y);
#pragma unroll
        for (int off = 1; off < 64; off <<= 1) {       // 4 interleaved chains
            m0 = fmaxf(m0, __shfl_xor(m0, off));
            m1 = fmaxf(m1, __shfl_xor(m1, off));
            m2 = fmaxf(m2, __shfl_xor(m2, off));
            m3 = fmaxf(m3, __shfl_xor(m3, off));
        }
        if (lane == 0)
            *(float4*)&pm[part * NRAYS + rbase + r] = make_float4(m0, m1, m2, m3);
    }
}

// ---------------------------------------------------------------------------
// scan: inline theta-reduce prologue (wave 0: coalesced pm reads, branchless
// top-10 insert -> theta in rsh[].w), 16 pts/lane as 8 packed pairs, emit all
// points with score >= theta to per-ray LDS, bulk flush -> cand.
// ---------------------------------------------------------------------------
__global__ __launch_bounds__(256) void scan_kernel(const float* __restrict__ xyz,
                                                   const float* __restrict__ ro,
                                                   const float* __restrict__ rd,
                                                   const float* __restrict__ pm,
                                                   int* __restrict__ cnt,
                                                   float2* __restrict__ cand) {
    __shared__ float4 rsh[RPBS];
    __shared__ int    lcnt[RPBS];
    __shared__ float2 lbuf[RPBS][LCAP];
    const int pblk = blockIdx.x, rchunk = blockIdx.y;
    const int tid = threadIdx.x, wave = tid >> 6, lane = tid & 63;
    const int rbase = rchunk * RPBS;

    if (tid < RPBS) {
        // theta = 10th-largest of 64 part maxima for ray rbase+tid (branchless)
        float vs[KTOP];
#pragma unroll
        for (int j = 0; j < KTOP; ++j) vs[j] = -INFINITY;
#pragma unroll
        for (int g = 0; g < NPART / 8; ++g) {
            float m[8];
#pragma unroll
            for (int j = 0; j < 8; ++j) m[j] = pm[(g * 8 + j) * NRAYS + rbase + tid];
#pragma unroll
            for (int j = 0; j < 8; ++j) {
                float v = m[j];
#pragma unroll
                for (int t = KTOP - 1; t >= 1; --t) {
                    bool up = v > vs[t - 1], here = v > vs[t];
                    vs[t] = up ? vs[t - 1] : (here ? v : vs[t]);
                }
                vs[0] = fmaxf(vs[0], v);
            }
        }
        rsh[tid] = make_center(ro, rd, rbase + tid, vs[KTOP - 1]);
        lcnt[tid] = 0;
    }

    const int id0 = pblk * 4096 + wave * 1024 + lane;
    v2f px[PPAIR], py[PPAIR], pz[PPAIR], pw[PPAIR];
#pragma unroll
    for (int u = 0; u < PPAIR; ++u) {
        int ia = id0 + (2 * u) * 64, ib = id0 + (2 * u + 1) * 64;
        bool va = ia < NPTS, vb = ib < NPTS;
        int ca = va ? ia : 0, cb = vb ? ib : 0;
        float xa = xyz[3 * ca + 0], ya = xyz[3 * ca + 1], za = xyz[3 * ca + 2];
        float xb = xyz[3 * cb + 0], yb = xyz[3 * cb + 1], zb = xyz[3 * cb + 2];
        px[u] = (v2f){xa, xb}; py[u] = (v2f){ya, yb}; pz[u] = (v2f){za, zb};
        pw[u] = (v2f){va ? -0.5f * fmaf(xa, xa, fmaf(ya, ya, za * za)) : -INFINITY,
                      vb ? -0.5f * fmaf(xb, xb, fmaf(yb, yb, zb * zb)) : -INFINITY};
    }
    __syncthreads();

    float4 rp = rsh[0], rp1 = rsh[1];
    for (int r = 0; r < RPBS; ++r) {
        float4 rp2 = rsh[(r + 2) & (RPBS - 1)];        // 2-ahead prefetch
        const v2f rx = (v2f){rp.x, rp.x}, ry = (v2f){rp.y, rp.y}, rz = (v2f){rp.z, rp.z};
        v2f s[PPAIR];
        v2f a0 = (v2f){-INFINITY, -INFINITY}, a1 = a0;
#pragma unroll
        for (int u = 0; u < PPAIR; u += 2) {
            v2f t0 = __builtin_elementwise_fma(pz[u], rz, pw[u]);
            t0 = __builtin_elementwise_fma(py[u], ry, t0);
            t0 = __builtin_elementwise_fma(px[u], rx, t0);
            s[u] = t0;
            a0 = __builtin_elementwise_max(a0, t0);
            v2f t1 = __builtin_elementwise_fma(pz[u + 1], rz, pw[u + 1]);
            t1 = __builtin_elementwise_fma(py[u + 1], ry, t1);
            t1 = __builtin_elementwise_fma(px[u + 1], rx, t1);
            s[u + 1] = t1;
            a1 = __builtin_elementwise_max(a1, t1);
        }
        v2f am = __builtin_elementwise_max(a0, a1);
        float hm = fmaxf(am.x, am.y);

        if (__ballot(hm >= rp.w)) {                    // rare wave-level branch
#pragma unroll
            for (int u = 0; u < PPAIR; ++u) {
                if (s[u].x >= rp.w) {
                    int slot = atomicAdd(&lcnt[r], 1);
                    float2 e = make_float2(s[u].x, __int_as_float(id0 + (2 * u) * 64));
                    if (slot < LCAP) lbuf[r][slot] = e;
                    else {
                        int gs = atomicAdd(&cnt[rbase + r], 1);
                        if (gs < CAP) cand[((rbase + r) << 7) + gs] = e;
                    }
                }
                if (s[u].y >= rp.w) {
                    int slot = atomicAdd(&lcnt[r], 1);
                    float2 e = make_float2(s[u].y, __int_as_float(id0 + (2 * u + 1) * 64));
                    if (slot < LCAP) lbuf[r][slot] = e;
                    else {
                        int gs = atomicAdd(&cnt[rbase + r], 1);
                        if (gs < CAP) cand[((rbase + r) << 7) + gs] = e;
                    }
                }
            }
        }
        rp = rp1; rp1 = rp2;
    }

    __syncthreads();
    if (tid < RPBS) {                                  // bulk flush: 1 atomic/ray
        int n = lcnt[tid];
        n = n < LCAP ? n : LCAP;
        if (n > 0) {
            const int rayid = rbase + tid;
            int base = atomicAdd(&cnt[rayid], n);
            for (int j = 0; j < n; ++j) {
                int slot = base + j;
                if (slot < CAP) cand[(rayid << 7) + slot] = lbuf[tid][j];
            }
        }
    }
}

// ---------------------------------------------------------------------------
// merge: wave per ray (proven R6 body). Coalesced candidate load, top-12 via
// 12 wave-argmax rounds on packed keys, parallel f64 re-rank, rgb.
// ---------------------------------------------------------------------------
__global__ __launch_bounds__(256) void merge_kernel(const float* __restrict__ ro,
                                                    const float* __restrict__ rd,
                                                    const int* __restrict__ cnt,
                                                    const float2* __restrict__ cand,
                                                    const float* __restrict__ xyz,
                                                    const float* __restrict__ fdc,
                                                    const float* __restrict__ opac,
                                                    float* __restrict__ out) {
    const int wave = threadIdx.x >> 6, lane = threadIdx.x & 63;
    const int ray = blockIdx.x * 4 + wave;

    int n = cnt[ray];
    n = n < CAP ? n : CAP;

    const float2* cl = cand + (ray << 7);
    float2 e0 = cl[lane];                              // coalesced 512B wave-load
    float2 e1 = cl[64 + lane];
    int id0 = __float_as_int(e0.y), id1 = __float_as_int(e1.y);

    unsigned long long k0 = mkkey(e0.x, id0, lane < n);
    unsigned long long k1 = mkkey(e1.x, id1, lane + 64 < n);

    int sel = -1;                                      // lane j holds j-th best id
    unsigned long long kl = k0 > k1 ? k0 : k1;
#pragma unroll
    for (int j = 0; j < KMER; ++j) {
        unsigned long long m = kl;
#pragma unroll
        for (int off = 1; off < 64; off <<= 1) {
            unsigned long long o = __shfl_xor(m, off);
            m = m > o ? m : o;
        }
        bool win = (kl == m) && (m != 0ull);
        int wid = (k0 >= k1) ? id0 : id1;
        unsigned long long wmask = __ballot(win);
        int wl = __ffsll(wmask) - 1;                   // unique winner (keys unique)
        int bid = __shfl(wid, wl & 63);
        if (m == 0ull) bid = -1;
        if (lane == j) sel = bid;
        if (win) {
            if (k0 >= k1) k0 = 0ull; else k1 = 0ull;
            kl = k0 > k1 ? k0 : k1;
        }
    }

    float ox = ro[3 * ray + 0], oy = ro[3 * ray + 1], oz = ro[3 * ray + 2];
    float dx = rd[3 * ray + 0], dy = rd[3 * ray + 1], dz = rd[3 * ray + 2];
    float cxf, cyf, czf;
    {
#pragma clang fp contract(off)
        cxf = ox + dx * 3.0f;
        cyf = oy + dy * 3.0f;
        czf = oz + dz * 3.0f;
    }
    double Cx = (double)cxf, Cy = (double)cyf, Cz = (double)czf;
    double cn = Cx * Cx + Cy * Cy + Cz * Cz;

    bool valid = (lane < KMER) && (sel >= 0);
    int pid = valid ? sel : 0;
    double X = (double)xyz[3 * pid + 0];
    double Y = (double)xyz[3 * pid + 1];
    double Z = (double)xyz[3 * pid + 2];
    double sq = valid ? (cn + (X * X + Y * Y + Z * Z) - 2.0 * (Cx * X + Cy * Y + Cz * Z))
                      : (double)INFINITY;
    int cid = valid ? sel : 0x7fffffff;

    int rank = 0;
#pragma unroll
    for (int k = 0; k < KMER; ++k) {                   // rank among the 12
        double sk = __shfl(sq, k);
        int    ik = __shfl(cid, k);
        if ((sk < sq) || (sk == sq && ik < cid)) ++rank;
    }

    bool take = valid && (rank < KTOP);
    float w = 0.0f, rr = 0.0f, gg = 0.0f, bb = 0.0f;
    if (take) {                                        // parallel gathers, 10 lanes
        float dd = sqrtf(fmaxf((float)sq, 0.0f));
        w  = expf(-0.1f * dd) * sigm(opac[pid]);
        rr = w * sigm(fdc[3 * pid + 0]);
        gg = w * sigm(fdc[3 * pid + 1]);
        bb = w * sigm(fdc[3 * pid + 2]);
    }
#pragma unroll
    for (int off = 1; off < 64; off <<= 1) {
        w  += __shfl_xor(w,  off);
        rr += __shfl_xor(rr, off);
        gg += __shfl_xor(gg, off);
        bb += __shfl_xor(bb, off);
    }
    if (lane == 0) {
        float inv = 1.0f / (w + 1e-8f);
        out[3 * ray + 0] = rr * inv;
        out[3 * ray + 1] = gg * inv;
        out[3 * ray + 2] = bb * inv;
    }
}

// ---------------------------------------------------------------------------
extern "C" void kernel_launch(void* const* d_in, const int* in_sizes, int n_in,
                              void* d_out, int out_size, void* d_ws, size_t ws_size,
                              hipStream_t stream) {
    const float* rays_o = (const float*)d_in[0];
    const float* rays_d = (const float*)d_in[1];
    const float* xyz    = (const float*)d_in[2];
    const float* fdc    = (const float*)d_in[3];
    const float* opac   = (const float*)d_in[4];
    float* out = (float*)d_out;

    // ws: pm 1.0MB | cnt 16KB | cand 4.0MB  (~5.1MB total)
    char* w = (char*)d_ws;
    float*  pm    = (float*)w;   w += (size_t)NPART * NRAYS * 4;
    int*    cnt   = (int*)w;     w += (size_t)NRAYS * 4;
    float2* cand  = (float2*)w;

    theta_part_kernel<<<dim3(TBLK, RCT), 256, 0, stream>>>(xyz, rays_o, rays_d, pm, cnt);
    scan_kernel<<<dim3(SBLK, RCS), 256, 0, stream>>>(xyz, rays_o, rays_d, pm, cnt, cand);
    merge_kernel<<<NRAYS / 4, 256, 0, stream>>>(rays_o, rays_d, cnt, cand, xyz, fdc, opac, out);
}